// Round 9
// baseline (142.381 us; speedup 1.0000x reference)
//
#include <hip/hip_runtime.h>

// Problem constants
#define BATCH 64
#define NNODE 1024
#define FDIM  200
#define MROWS (BATCH * NNODE)   // 65536
#define NEG_SLOPE 0.2f

#define NKT 7                   // k-tiles of 32 (K 200 -> 224)
#define NNT 13                  // n-tiles of 16 (N 200 -> 208)

typedef short s16x8 __attribute__((ext_vector_type(8)));
typedef float f32x4 __attribute__((ext_vector_type(4)));

// ws layout (bytes) — total 537,600 (below round-6's proven watermark):
//   h0frag : bf16 B-frags of h0, (kt2*13+nt)*1024, kt2<32  @ 0       (425,984)
//   a_s    : float[1024] @ 425984
//   a_d    : float[1024] @ 430080
//   m_i    : float[1024] @ 434176
//   l_i    : float[1024] @ 438272
//   wsv    : float[200]  @ 442368
//   wdv    : float[200]  @ 443168
//   fragW  : bf16 B-frags of W, (kt*13+nt)*1024, kt<7 @ 444416 (93,184)

__device__ __forceinline__ unsigned int f2bf(float f) {
    unsigned int u = __float_as_uint(f);
    return (u + 0x7fffu + ((u >> 16) & 1u)) >> 16;
}
__device__ __forceinline__ unsigned int pack2(float a, float b) {
    return f2bf(a) | (f2bf(b) << 16);
}

// ---------------------------------------------------------------------------
// k_prep: blocks 0..90  : W -> bf16 B-fragments (16x16x32 layout), 224x208 pad
//         blocks 91..290: wsv[k]/wdv[k] = dot(W[k,:], att_src/att_dst)
// ---------------------------------------------------------------------------
__global__ __launch_bounds__(64) void k_prep(const float* __restrict__ W,
                                             const float* __restrict__ att_src,
                                             const float* __restrict__ att_dst,
                                             unsigned short* __restrict__ fragW,
                                             float* __restrict__ wsv,
                                             float* __restrict__ wdv)
{
    const int b    = blockIdx.x;
    const int lane = threadIdx.x;

    if (b < 91) {
        const int kt = b / NNT;
        const int nt = b - kt * NNT;
        const int n  = nt * 16 + (lane & 15);
        const int kb = kt * 32 + (lane >> 4) * 8;
        s16x8 v;
        #pragma unroll
        for (int j = 0; j < 8; ++j) {
            int k = kb + j;
            float f = (k < FDIM && n < FDIM) ? W[k * FDIM + n] : 0.f;
            v[j] = (short)f2bf(f);
        }
        ((s16x8*)(fragW + (size_t)b * 512))[lane] = v;
    } else {
        const int kk = b - 91;               // [0, 200)
        const float* Wr = W + kk * FDIM;
        float ps = 0.f, pd = 0.f;
        #pragma unroll
        for (int i = 0; i < 4; ++i) {
            int n = lane + i * 64;
            if (n < FDIM) {
                float wv = Wr[n];
                ps = fmaf(wv, att_src[n], ps);
                pd = fmaf(wv, att_dst[n], pd);
            }
        }
        #pragma unroll
        for (int off = 32; off; off >>= 1) {
            ps += __shfl_down(ps, off);
            pd += __shfl_down(pd, off);
        }
        if (lane == 0) { wsv[kk] = ps; wdv[kk] = pd; }
    }
}

// ---------------------------------------------------------------------------
// k_av: a_s = x0 @ wsv, a_d = x0 @ wdv  (reassociated (x@W)@att = x@(W@att)).
// ---------------------------------------------------------------------------
__global__ __launch_bounds__(256) void k_av(const float* __restrict__ x,
                                            const float* __restrict__ wsv,
                                            const float* __restrict__ wdv,
                                            float* __restrict__ a_s,
                                            float* __restrict__ a_d)
{
    const int tid  = threadIdx.x;
    const int lane = tid & 63;
    const int row  = blockIdx.x * 4 + (tid >> 6);
    const float* xr = x + (size_t)row * FDIM;
    float ss = 0.f, sd = 0.f;
    for (int k = lane; k < FDIM; k += 64) {
        float xv = xr[k];
        ss = fmaf(xv, wsv[k], ss);
        sd = fmaf(xv, wdv[k], sd);
    }
    #pragma unroll
    for (int off = 32; off; off >>= 1) {
        ss += __shfl_down(ss, off);
        sd += __shfl_down(sd, off);
    }
    if (lane == 0) { a_s[row] = ss; a_d[row] = sd; }
}

// ---------------------------------------------------------------------------
// k_stats: per-row softmax stats. lrelu monotone => row max = lrelu(ad + max a_s).
// ---------------------------------------------------------------------------
__global__ __launch_bounds__(256) void k_stats(const float* __restrict__ a_s,
                                               const float* __restrict__ a_d,
                                               float* __restrict__ m_out,
                                               float* __restrict__ l_out)
{
    __shared__ float as_s[1024];
    const int tid = threadIdx.x;
    #pragma unroll
    for (int i = 0; i < 4; ++i) as_s[tid + i * 256] = a_s[tid + i * 256];
    __syncthreads();

    const int lane = tid & 63;
    const int row  = blockIdx.x * 4 + (tid >> 6);

    float mx = -1e30f;
    #pragma unroll
    for (int i = 0; i < 16; ++i) mx = fmaxf(mx, as_s[lane + i * 64]);
    #pragma unroll
    for (int off = 32; off; off >>= 1) mx = fmaxf(mx, __shfl_down(mx, off));
    mx = __shfl(mx, 0);

    const float ad = a_d[row];
    float mi = ad + mx; mi = (mi > 0.f) ? mi : NEG_SLOPE * mi;

    float sum = 0.f;
    #pragma unroll
    for (int i = 0; i < 16; ++i) {
        float s = ad + as_s[lane + i * 64];
        s = (s > 0.f) ? s : NEG_SLOPE * s;
        sum += __expf(s - mi);
    }
    #pragma unroll
    for (int off = 32; off; off >>= 1) sum += __shfl_down(sum, off);
    if (lane == 0) { m_out[row] = mi; l_out[row] = sum; }
}

// ---------------------------------------------------------------------------
// k_gemm: h = x @ W. 512 blocks x 256 thr; wave w owns 32 rows (2 subtiles).
// fragW staged into 52 KB LDS in TWO phases (kt 0..3, then kt 4..6);
// accumulators persist across phases. A-frags straight from global
// (coalesced dwordx4 + bf16 pack), B via ds_read_b128.
// All rows: out = h + bias. Blocks 0..7 (rows < 1024) also transpose their
// C-tiles into h0frag (bf16 B-frag layout) via per-wave LDS scratch
// (block-uniform __syncthreads). k_attn later overwrites out rows < 1024.
// ---------------------------------------------------------------------------
__global__ __launch_bounds__(256) void k_gemm(const float* __restrict__ x,
                                              const uint4* __restrict__ fragWg,
                                              const float* __restrict__ bias,
                                              float* __restrict__ out,
                                              unsigned short* __restrict__ h0frag)
{
    __shared__ uint4 ldsW4[52 * 64];           // 53,248 B (4 kt x 13 nt frags)
    __shared__ float scr[4][16][17];           // 4,352 B per-wave transpose scratch
    unsigned short* ldsW = (unsigned short*)ldsW4;
    const int tid  = threadIdx.x;
    const int lane = tid & 63;
    const int w    = __builtin_amdgcn_readfirstlane(tid >> 6);
    const int ln   = lane & 15;
    const int quad = lane >> 4;
    const int R0   = blockIdx.x * 128 + w * 32;

    f32x4 acc[2][NNT];
    #pragma unroll
    for (int s = 0; s < 2; ++s)
        #pragma unroll
        for (int nt = 0; nt < NNT; ++nt) acc[s][nt] = (f32x4){0.f, 0.f, 0.f, 0.f};

    // ---- phase 0: stage kt 0..3 (52 frags = 3328 uint4 = 13*256)
    #pragma unroll
    for (int i = 0; i < 13; ++i)
        ldsW4[tid + i * 256] = fragWg[tid + i * 256];
    __syncthreads();

    #pragma unroll
    for (int kt = 0; kt < 4; ++kt) {
        s16x8 a[2];
        #pragma unroll
        for (int s = 0; s < 2; ++s) {
            const float4* ap = (const float4*)(x +
                (size_t)(R0 + s * 16 + ln) * FDIM + kt * 32 + quad * 8);
            float4 f0 = ap[0], f1 = ap[1];
            unsigned int au[4] = {pack2(f0.x, f0.y), pack2(f0.z, f0.w),
                                  pack2(f1.x, f1.y), pack2(f1.z, f1.w)};
            a[s] = *(s16x8*)au;
        }
        #pragma unroll
        for (int nt = 0; nt < NNT; ++nt) {
            s16x8 bf = *(const s16x8*)(ldsW + (kt * NNT + nt) * 512 + lane * 8);
            #pragma unroll
            for (int s = 0; s < 2; ++s)
                acc[s][nt] = __builtin_amdgcn_mfma_f32_16x16x32_bf16(
                    a[s], bf, acc[s][nt], 0, 0, 0);
        }
    }

    // ---- phase 1: stage kt 4..6 (39 frags = 2496 uint4)
    __syncthreads();
    #pragma unroll
    for (int i = 0; i < 10; ++i) {
        int idx = tid + i * 256;
        if (idx < 2496) ldsW4[idx] = fragWg[3328 + idx];
    }
    __syncthreads();

    #pragma unroll
    for (int kt = 4; kt < NKT; ++kt) {
        s16x8 a[2];
        #pragma unroll
        for (int s = 0; s < 2; ++s) {
            if (kt < 6 || quad == 0) {       // kt==6: only k 192..199 valid
                const float4* ap = (const float4*)(x +
                    (size_t)(R0 + s * 16 + ln) * FDIM + kt * 32 + quad * 8);
                float4 f0 = ap[0], f1 = ap[1];
                unsigned int au[4] = {pack2(f0.x, f0.y), pack2(f0.z, f0.w),
                                      pack2(f1.x, f1.y), pack2(f1.z, f1.w)};
                a[s] = *(s16x8*)au;
            } else {
                a[s] = (s16x8){0, 0, 0, 0, 0, 0, 0, 0};
            }
        }
        #pragma unroll
        for (int nt = 0; nt < NNT; ++nt) {
            s16x8 bf = *(const s16x8*)(ldsW + ((kt - 4) * NNT + nt) * 512 + lane * 8);
            #pragma unroll
            for (int s = 0; s < 2; ++s)
                acc[s][nt] = __builtin_amdgcn_mfma_f32_16x16x32_bf16(
                    a[s], bf, acc[s][nt], 0, 0, 0);
        }
    }

    // ---- epilogue. D: col = nt*16 + ln, row = R0 + s*16 + quad*4 + r
    #pragma unroll
    for (int nt = 0; nt < NNT; ++nt) {
        int col = nt * 16 + ln;
        if (nt < 12 || ln < 8) {
            float bv = bias[col];
            #pragma unroll
            for (int s = 0; s < 2; ++s)
                #pragma unroll
                for (int r = 0; r < 4; ++r)
                    out[(size_t)(R0 + s * 16 + quad * 4 + r) * FDIM + col]
                        = acc[s][nt][r] + bv;
        }
    }

    // ---- rows < 1024 (blocks 0..7, block-uniform): transpose raw h into
    //      h0frag bf16 B-frag layout. Wave's subtile s covers global rows
    //      Rg..Rg+15 = half 'lo' of frag row-group kt2.
    if (blockIdx.x < 8) {
        #pragma unroll
        for (int s = 0; s < 2; ++s) {
            const int Rg  = R0 + s * 16;
            const int kt2 = Rg >> 5;
            const int lo  = (Rg >> 4) & 1;
            for (int nt = 0; nt < NNT; ++nt) {
                #pragma unroll
                for (int r = 0; r < 4; ++r) scr[w][quad * 4 + r][ln] = acc[s][nt][r];
                __syncthreads();
                if (lane < 32) {             // half-frag: lane = oct*16 + nl
                    int oct = lane >> 4, nl = lane & 15;
                    uint4 dv;
                    dv.x = pack2(scr[w][oct * 8 + 0][nl], scr[w][oct * 8 + 1][nl]);
                    dv.y = pack2(scr[w][oct * 8 + 2][nl], scr[w][oct * 8 + 3][nl]);
                    dv.z = pack2(scr[w][oct * 8 + 4][nl], scr[w][oct * 8 + 5][nl]);
                    dv.w = pack2(scr[w][oct * 8 + 6][nl], scr[w][oct * 8 + 7][nl]);
                    *(uint4*)(h0frag +
                        ((size_t)(kt2 * NNT + nt) * 64 + lo * 32 + lane) * 8) = dv;
                }
                __syncthreads();
            }
        }
    }
}

// ---------------------------------------------------------------------------
// k_attn: out0 = alpha @ h0 + bias. Alpha computed in-register EXACTLY ONCE
// per (i,j) (no alphafrag buffer, no atomics). 64 blocks x 256 thr.
// Block = 16 alpha-rows (i0 = blk*16). Wave w: kt2 in [8w, 8w+8) (256 j).
// Per kt2: 8 exps/lane -> A-frag; 13 B-frags from h0frag (L2) + 13 MFMA.
// Cross-wave reduce via LDS f32x4, direct store with bias.
// ---------------------------------------------------------------------------
__global__ __launch_bounds__(256) void k_attn(const unsigned short* __restrict__ h0frag,
                                              const float* __restrict__ a_s,
                                              const float* __restrict__ a_d,
                                              const float* __restrict__ m_v,
                                              const float* __restrict__ l_v,
                                              const float* __restrict__ bias,
                                              float* __restrict__ out)
{
    __shared__ f32x4 red[4][64][NNT];        // 53,248 B
    const int tid  = threadIdx.x;
    const int lane = tid & 63;
    const int w    = __builtin_amdgcn_readfirstlane(tid >> 6);
    const int ln   = lane & 15;
    const int quad = lane >> 4;
    const int i0   = blockIdx.x * 16;

    const float ad = a_d[i0 + ln];
    const float mi = m_v[i0 + ln];
    const float rl = 1.0f / l_v[i0 + ln];

    f32x4 acc[NNT];
    #pragma unroll
    for (int nt = 0; nt < NNT; ++nt) acc[nt] = (f32x4){0.f, 0.f, 0.f, 0.f};

    #pragma unroll
    for (int kk = 0; kk < 8; ++kk) {
        const int kt2 = w * 8 + kk;
        const float4* ap = (const float4*)(a_s + kt2 * 32 + quad * 8);
        float4 f0 = ap[0], f1 = ap[1];
        float e[8] = {f0.x, f0.y, f0.z, f0.w, f1.x, f1.y, f1.z, f1.w};
        #pragma unroll
        for (int jj = 0; jj < 8; ++jj) {
            float s = ad + e[jj];
            s = (s > 0.f) ? s : NEG_SLOPE * s;
            e[jj] = __expf(s - mi) * rl;     // alpha, 1/l folded (i = ln = A's m)
        }
        unsigned int au[4] = {pack2(e[0], e[1]), pack2(e[2], e[3]),
                              pack2(e[4], e[5]), pack2(e[6], e[7])};
        s16x8 afrag = *(s16x8*)au;
        #pragma unroll
        for (int nt = 0; nt < NNT; ++nt) {
            s16x8 bf = *(const s16x8*)(h0frag +
                ((size_t)(kt2 * NNT + nt) * 64 + lane) * 8);
            acc[nt] = __builtin_amdgcn_mfma_f32_16x16x32_bf16(afrag, bf, acc[nt], 0, 0, 0);
        }
    }

    #pragma unroll
    for (int nt = 0; nt < NNT; ++nt) red[w][lane][nt] = acc[nt];
    __syncthreads();

    for (int nt = w; nt < NNT; nt += 4) {
        f32x4 v = red[0][lane][nt];
        #pragma unroll
        for (int p = 1; p < 4; ++p) v += red[p][lane][nt];
        const int col = nt * 16 + ln;
        if (col < FDIM) {
            float bv = bias[col];
            #pragma unroll
            for (int r = 0; r < 4; ++r)
                out[(size_t)(i0 + quad * 4 + r) * FDIM + col] = v[r] + bv;
        }
    }
}

// ---------------------------------------------------------------------------
extern "C" void kernel_launch(void* const* d_in, const int* in_sizes, int n_in,
                              void* d_out, int out_size, void* d_ws, size_t ws_size,
                              hipStream_t stream)
{
    const float* x       = (const float*)d_in[0];
    const float* W       = (const float*)d_in[1];
    const float* att_src = (const float*)d_in[2];
    const float* att_dst = (const float*)d_in[3];
    const float* bias    = (const float*)d_in[4];
    float* out = (float*)d_out;
    char*  wsb = (char*)d_ws;

    unsigned short* h0frag = (unsigned short*)(wsb + 0);        // 425,984 B
    float* a_s = (float*)(wsb + 425984);
    float* a_d = (float*)(wsb + 430080);
    float* m_i = (float*)(wsb + 434176);
    float* l_i = (float*)(wsb + 438272);
    float* wsv = (float*)(wsb + 442368);
    float* wdv = (float*)(wsb + 443168);
    unsigned short* fragW = (unsigned short*)(wsb + 444416);    // 93,184 B

    k_prep <<<291,         64, 0, stream>>>(W, att_src, att_dst, fragW, wsv, wdv);
    k_av   <<<NNODE / 4,  256, 0, stream>>>(x, wsv, wdv, a_s, a_d);
    k_stats<<<NNODE / 4,  256, 0, stream>>>(a_s, a_d, m_i, l_i);
    k_gemm <<<MROWS / 128, 256, 0, stream>>>(x, (const uint4*)fragW, bias, out, h0frag);
    k_attn <<<64,         256, 0, stream>>>(h0frag, a_s, a_d, m_i, l_i, bias, out);
}